// Round 3
// baseline (137.846 us; speedup 1.0000x reference)
//
#include <hip/hip_runtime.h>
#include <hip/hip_bf16.h>

#define NNODE 512
#define CCH   16
#define TT    15
#define TP    16   // T+1, also padded t dimension
#define HH    32
#define DD    32

typedef unsigned short u16;
typedef unsigned int   u32;

__device__ __forceinline__ float bf2f(u16 v) {
    union { u32 u; float f; } x; x.u = ((u32)v) << 16; return x.f;
}
__device__ __forceinline__ u16 f2bf(float f) {
    union { float f; u32 u; } x; x.f = f;
    u32 u = x.u;
    u32 r = (u + 0x7FFFu + ((u >> 16) & 1u)) >> 16;
    return (u16)r;
}
__device__ __forceinline__ void unpack8(uint4 p, float* o) {
    o[0]=bf2f((u16)(p.x & 0xffffu)); o[1]=bf2f((u16)(p.x >> 16));
    o[2]=bf2f((u16)(p.y & 0xffffu)); o[3]=bf2f((u16)(p.y >> 16));
    o[4]=bf2f((u16)(p.z & 0xffffu)); o[5]=bf2f((u16)(p.z >> 16));
    o[6]=bf2f((u16)(p.w & 0xffffu)); o[7]=bf2f((u16)(p.w >> 16));
}

// Dtype self-detection: scan first 64 u16 of the buffer. Real bf16 data has
// all exponents in a sane band; f32 data's mantissa-low-halves have ~uniform
// exponents and flag within a few entries. Deterministic, block-uniform.
__device__ __forceinline__ bool detect_f32(const void* p) {
    const u16* w = (const u16*)p;
    bool f32 = false;
    #pragma unroll
    for (int k = 0; k < 64; k++) {
        u32 e = (w[k] >> 7) & 0xFFu;
        if (e != 0u && (e < 0x5Cu || e > 0x94u)) f32 = true;
    }
    return f32;
}
__device__ __forceinline__ float ldin(const void* p, size_t i, bool f32) {
    return f32 ? ((const float*)p)[i] : bf2f(((const u16*)p)[i]);
}

// ---------------------------------------------------------------------------
// Kernel 1: small precomputes. One block per node n.
// A1[n,t,h]=sum_i x[n,i]W1[i,t,h]; B1 uses W1[C+i]; A2/B2 from W2; Q=x@W3;
// QAd[n,t]=Q[n]·A1[n,t,:]; QB[n,t]=Q[n]·B1[n,t,:]
// ---------------------------------------------------------------------------
__global__ __launch_bounds__(256) void k_prep(
    const void* __restrict__ xv, const void* __restrict__ W1v,
    const void* __restrict__ W2v, const void* __restrict__ W3v,
    u16* __restrict__ A1, u16* __restrict__ B1,
    u16* __restrict__ A2, u16* __restrict__ B2,
    float* __restrict__ Q, float* __restrict__ QAd, float* __restrict__ QB)
{
    const bool f32 = detect_f32(xv);   // uniform dtype across all inputs
    int n = blockIdx.x;
    int tid = threadIdx.x;
    __shared__ alignas(16) float xs[CCH];
    __shared__ alignas(16) float A1row[512], B1row[512];
    __shared__ alignas(16) float Qs[HH];
    if (tid < CCH) xs[tid] = ldin(xv, (size_t)n*CCH + tid, f32);
    __syncthreads();
    float xr[CCH];
    #pragma unroll
    for (int i=0;i<CCH;i++) xr[i]=xs[i];

    #pragma unroll
    for (int rep=0; rep<2; rep++) {
        int c = tid + rep*256;   // c = t*32 + h (or t*32 + d), 0..511
        float a1=0.f,b1=0.f,a2=0.f,b2=0.f;
        #pragma unroll
        for (int i=0;i<CCH;i++) {
            a1 += xr[i]*ldin(W1v, (size_t)i*512 + c, f32);
            b1 += xr[i]*ldin(W1v, (size_t)(CCH+i)*512 + c, f32);
            a2 += xr[i]*ldin(W2v, (size_t)i*512 + c, f32);
            b2 += xr[i]*ldin(W2v, (size_t)(CCH+i)*512 + c, f32);
        }
        A1[(size_t)n*512 + c]=f2bf(a1); B1[(size_t)n*512 + c]=f2bf(b1);
        A2[(size_t)n*512 + c]=f2bf(a2); B2[(size_t)n*512 + c]=f2bf(b2);
        A1row[c]=a1; B1row[c]=b1;
    }
    if (tid < HH) {
        float q=0.f;
        #pragma unroll
        for (int i=0;i<CCH;i++) q += xr[i]*ldin(W3v, (size_t)i*HH + tid, f32);
        Qs[tid]=q; Q[(size_t)n*HH + tid]=q;
    }
    __syncthreads();
    if (tid < TP) {
        float qa=0.f, qb=0.f;
        #pragma unroll
        for (int h=0;h<HH;h++) { qa += Qs[h]*A1row[tid*HH+h]; qb += Qs[h]*B1row[tid*HH+h]; }
        QAd[(size_t)n*TP + tid]=qa; QB[(size_t)n*TP + tid]=qb;
    }
}

// ---------------------------------------------------------------------------
// Kernel 2: build padded adjacency adjP[n][m][16] bf16, slot 15 = (n==m)?1:0.
// This folds the diagonal (t=T) term of D into the t-sum exactly.
// ---------------------------------------------------------------------------
__global__ __launch_bounds__(256) void k_adjp(const void* __restrict__ adjv, u16* __restrict__ adjP)
{
    const bool f32 = detect_f32(adjv);
    int p = blockIdx.x*256 + threadIdx.x;   // pair index 0..262143
    int n = p >> 9, m = p & 511;
    u16 v[TP];
    #pragma unroll
    for (int t=0;t<TT;t++) v[t]=f2bf(ldin(adjv, (size_t)p*TT + t, f32));
    v[TT] = (n==m) ? (u16)0x3F80 : (u16)0;  // bf16 1.0 / 0.0
    uint4* d4 = (uint4*)(adjP + (size_t)p*TP);
    uint4 w0 = make_uint4((u32)v[0]|((u32)v[1]<<16), (u32)v[2]|((u32)v[3]<<16),
                          (u32)v[4]|((u32)v[5]<<16), (u32)v[6]|((u32)v[7]<<16));
    uint4 w1 = make_uint4((u32)v[8]|((u32)v[9]<<16), (u32)v[10]|((u32)v[11]<<16),
                          (u32)v[12]|((u32)v[13]<<16), (u32)v[14]|((u32)v[15]<<16));
    d4[0]=w0; d4[1]=w1;
}

// ---------------------------------------------------------------------------
// Kernel 3: logits. Block = 16n x 16m tile. thread: ml=tid&15, nl=tid>>4.
// l1[n,m] = sum_t adjP[n,m,t]*(Qn·A1[m,t]) + adjP[m,n,t]*QB[n,t]
// l2[n,m] = sum_t adjP[n,m,t]*QAd[m,t]    + adjP[m,n,t]*(Qm·B1[n,t])
// L2 stored transposed (L2T[m][n]) so both softmaxes are row-wise.
// ---------------------------------------------------------------------------
#define LROW 520   // 512 + 8 bf16 pad: row stride 1040B (=65*16, keeps 16B align)
__global__ __launch_bounds__(256) void k_logits(
    const u16* __restrict__ adjP,
    const u16* __restrict__ A1, const u16* __restrict__ B1,
    const float* __restrict__ Q, const float* __restrict__ QAd, const float* __restrict__ QB,
    float* __restrict__ L1, float* __restrict__ L2T)
{
    const int m0 = blockIdx.x * 16;
    const int n0 = blockIdx.y * 16;
    const int tid = threadIdx.x;
    const int ml = tid & 15, nl = tid >> 4;

    __shared__ alignas(16) u16 smA1[16*LROW];
    __shared__ alignas(16) u16 smB1[16*LROW];
    __shared__ alignas(16) u16 smAdjMN[16*256];   // [m][n*16+t]
    __shared__ alignas(16) float smQAd[16*17];    // [m][t]
    __shared__ alignas(16) float smQB[16*17];     // [n][t]
    __shared__ alignas(16) float tr[16*17];

    {
        int row = tid >> 4, ch = tid & 15;
        const uint4* sA = (const uint4*)(A1 + (size_t)(m0+row)*512 + ch*32);
        uint4* dA = (uint4*)(smA1 + row*LROW + ch*32);
        dA[0]=sA[0]; dA[1]=sA[1]; dA[2]=sA[2]; dA[3]=sA[3];
        const uint4* sB = (const uint4*)(B1 + (size_t)(n0+row)*512 + ch*32);
        uint4* dB = (uint4*)(smB1 + row*LROW + ch*32);
        dB[0]=sB[0]; dB[1]=sB[1]; dB[2]=sB[2]; dB[3]=sB[3];
        // adjMN: rows m0..m0+15, cols n0..n0+15 (contiguous 512B per row)
        const uint4* sM = (const uint4*)(adjP + ((size_t)(m0+row)*512 + n0)*TP + ch*16);
        uint4* dM = (uint4*)(smAdjMN + row*256 + ch*16);
        dM[0]=sM[0]; dM[1]=sM[1];
        smQAd[row*17+ch] = QAd[(size_t)(m0+row)*TP + ch];
        smQB[row*17+ch]  = QB[(size_t)(n0+row)*TP + ch];
    }

    float qn[32], qm[32];
    #pragma unroll
    for (int h=0;h<32;h++) qn[h] = Q[(size_t)(n0+nl)*HH + h];
    #pragma unroll
    for (int h=0;h<32;h++) qm[h] = Q[(size_t)(m0+ml)*HH + h];

    // adjNM direct from global (coalesced 32B/lane)
    const uint4* pAdjA = (const uint4*)(adjP + ((size_t)(n0+nl)*512 + (m0+ml))*TP);
    uint4 aA0 = pAdjA[0], aA1 = pAdjA[1];
    float adjA[16];
    unpack8(aA0, adjA); unpack8(aA1, adjA+8);

    __syncthreads();

    const uint4* pAdjB = (const uint4*)(smAdjMN + ml*256 + nl*16);
    uint4 aB0 = pAdjB[0], aB1 = pAdjB[1];
    float adjB[16];
    unpack8(aB0, adjB); unpack8(aB1, adjB+8);

    float l1=0.f, l2=0.f;
    for (int t=0;t<TP;t++) {
        const uint4* pA = (const uint4*)(smA1 + ml*LROW + t*32);
        const uint4* pB = (const uint4*)(smB1 + nl*LROW + t*32);
        float dA=0.f, dB=0.f;
        #pragma unroll
        for (int q8=0;q8<4;q8++) {
            uint4 pa = pA[q8], pb = pB[q8];
            float av[8], bv[8];
            unpack8(pa, av); unpack8(pb, bv);
            #pragma unroll
            for (int h=0;h<8;h++) { dA += qn[q8*8+h]*av[h]; dB += qm[q8*8+h]*bv[h]; }
        }
        l1 = fmaf(adjA[t], dA, l1);
        l1 = fmaf(adjB[t], smQB[nl*17+t], l1);
        l2 = fmaf(adjA[t], smQAd[ml*17+t], l2);
        l2 = fmaf(adjB[t], dB, l2);
    }

    L1[(size_t)(n0+nl)*NNODE + m0+ml] = l1;     // coalesced (ml fast)
    tr[ml*17+nl] = l2;
    __syncthreads();
    {
        int r = tid >> 4, c = tid & 15;
        L2T[(size_t)(m0+r)*NNODE + n0+c] = tr[r*17+c];  // coalesced
    }
}

// ---------------------------------------------------------------------------
// Kernel 4: in-place row softmax. Blocks 0..511 -> rows of L1 (softmax over m);
// blocks 512..1023 -> rows of L2T (softmax over n, i.e. axis=0 of logits2).
// ---------------------------------------------------------------------------
__global__ __launch_bounds__(256) void k_softmax(float* __restrict__ L1, float* __restrict__ L2T)
{
    int b = blockIdx.x;
    float* row = (b < NNODE) ? (L1 + (size_t)b*NNODE) : (L2T + (size_t)(b-NNODE)*NNODE);
    int tid = threadIdx.x;
    float v0 = row[tid], v1 = row[tid+256];
    float m = fmaxf(v0, v1);
    #pragma unroll
    for (int o=32; o; o>>=1) m = fmaxf(m, __shfl_xor(m, o, 64));
    __shared__ alignas(16) float red[4];
    __shared__ alignas(16) float red2[4];
    int lane = tid & 63, wv = tid >> 6;
    if (!lane) red[wv] = m;
    __syncthreads();
    m = fmaxf(fmaxf(red[0],red[1]), fmaxf(red[2],red[3]));
    float e0 = __expf(v0 - m), e1 = __expf(v1 - m);
    float s = e0 + e1;
    #pragma unroll
    for (int o=32; o; o>>=1) s += __shfl_xor(s, o, 64);
    if (!lane) red2[wv] = s;
    __syncthreads();
    s = red2[0]+red2[1]+red2[2]+red2[3];
    float inv = 1.0f / s;
    row[tid] = e0*inv; row[tid+256] = e1*inv;
}

// ---------------------------------------------------------------------------
// Kernel 5: temp partials. Block = (j-tile of 16) x (k-chunk of 32).
// acc[j,d] += s1[j,k]*adjP[j,k,t]*A2[k,t,d] + s2T[j,k]*adjP[j,k,t]*B2[k,t,d]
// u1[j,t]  += s1[j,k]*adjP[k,j,t];  v2[j,t] += s2T[j,k]*adjP[k,j,t]
// thread: jl=tid>>4, c=tid&15 -> d pair (2c,2c+1); u/v slot t=c.
// ---------------------------------------------------------------------------
__global__ __launch_bounds__(256) void k_passc(
    const u16* __restrict__ adjP, const u16* __restrict__ A2, const u16* __restrict__ B2,
    const float* __restrict__ S1, const float* __restrict__ S2T,
    float* __restrict__ tempP, float* __restrict__ u1P, float* __restrict__ v2P)
{
    const int jt = blockIdx.x >> 4;
    const int kc = blockIdx.x & 15;
    const int j0 = jt * 16;
    const int k0 = kc * 32;
    const int tid = threadIdx.x;
    const int jl = tid >> 4, c = tid & 15;

    __shared__ alignas(16) u16 sA2[8*512];
    __shared__ alignas(16) u16 sB2[8*512];
    __shared__ alignas(16) u16 sAJK[16*128];  // [j][kk*16+t]
    __shared__ alignas(16) u16 sAKJ[8*256];   // [kk][j*16+t]
    __shared__ alignas(16) float sS1[16*9];
    __shared__ alignas(16) float sS2[16*9];

    float acc0=0.f, acc1=0.f, uacc=0.f, vacc=0.f;

    for (int kb=0; kb<4; kb++) {
        int kbase = k0 + kb*8;
        __syncthreads();
        {
            int row = tid >> 5, ch = tid & 31;   // 8 rows x 32 chunks of 16 u16
            const uint4* sa = (const uint4*)(A2 + (size_t)(kbase+row)*512 + ch*16);
            uint4* da = (uint4*)(sA2 + row*512 + ch*16);
            da[0]=sa[0]; da[1]=sa[1];
            const uint4* sb = (const uint4*)(B2 + (size_t)(kbase+row)*512 + ch*16);
            uint4* db = (uint4*)(sB2 + row*512 + ch*16);
            db[0]=sb[0]; db[1]=sb[1];
            // adjKJ: rows kbase..+7, cols j0..j0+15 : 256 u16 per row
            const uint4* sk = (const uint4*)(adjP + ((size_t)(kbase+row)*512 + j0)*TP + ch*8);
            uint4* dk = (uint4*)(sAKJ + row*256 + ch*8);
            dk[0]=sk[0];
        }
        {
            int j = tid >> 4, ch = tid & 15;     // 16 rows x 16 chunks of 8 u16
            const uint4* sj = (const uint4*)(adjP + ((size_t)(j0+j)*512 + kbase)*TP + ch*8);
            uint4* dj = (uint4*)(sAJK + j*128 + ch*8);
            dj[0]=sj[0];
        }
        if (tid < 128) {
            int j = tid >> 3, kk = tid & 7;
            sS1[j*9+kk] = S1[(size_t)(j0+j)*NNODE + kbase+kk];
            sS2[j*9+kk] = S2T[(size_t)(j0+j)*NNODE + kbase+kk];
        }
        __syncthreads();

        for (int kk=0; kk<8; kk++) {
            float s1v = sS1[jl*9+kk];
            float s2v = sS2[jl*9+kk];
            const uint4* pj = (const uint4*)(sAJK + jl*128 + kk*16);
            float at[16];
            unpack8(pj[0], at); unpack8(pj[1], at+8);
            #pragma unroll
            for (int t=0;t<TP;t++) {
                u32 pa = *(const u32*)(sA2 + kk*512 + t*32 + 2*c);
                u32 pb = *(const u32*)(sB2 + kk*512 + t*32 + 2*c);
                float w1 = s1v*at[t], w2 = s2v*at[t];
                acc0 += w1*bf2f((u16)(pa & 0xffffu)) + w2*bf2f((u16)(pb & 0xffffu));
                acc1 += w1*bf2f((u16)(pa >> 16))     + w2*bf2f((u16)(pb >> 16));
            }
            float akj = bf2f(sAKJ[kk*256 + jl*16 + c]);
            uacc += s1v*akj;
            vacc += s2v*akj;
        }
    }
    float2 o; o.x = acc0; o.y = acc1;
    *(float2*)(tempP + ((size_t)kc*NNODE + j0+jl)*DD + 2*c) = o;
    u1P[((size_t)kc*NNODE + j0+jl)*TP + c] = uacc;
    v2P[((size_t)kc*NNODE + j0+jl)*TP + c] = vacc;
}

// ---------------------------------------------------------------------------
// Kernel 6: reduce partials, add self terms, leaky-ReLU, write out (dtype
// matched to detected input dtype).
// ---------------------------------------------------------------------------
__global__ __launch_bounds__(256) void k_final(
    const float* __restrict__ tempP, const float* __restrict__ u1P, const float* __restrict__ v2P,
    const u16* __restrict__ A2, const u16* __restrict__ B2,
    const void* __restrict__ xv, void* __restrict__ outv)
{
    const bool f32 = detect_f32(xv);
    int j0 = blockIdx.x * 8;
    int tid = threadIdx.x;
    __shared__ alignas(16) float su[8*16];
    __shared__ alignas(16) float sv[8*16];
    if (tid < 128) {
        int j = tid >> 4, t = tid & 15;
        float us=0.f, vs=0.f;
        #pragma unroll
        for (int kc=0;kc<16;kc++) {
            us += u1P[((size_t)kc*NNODE + j0+j)*TP + t];
            vs += v2P[((size_t)kc*NNODE + j0+j)*TP + t];
        }
        su[j*16+t]=us; sv[j*16+t]=vs;
    }
    __syncthreads();
    int j = tid >> 5, d = tid & 31;
    float acc = 0.f;
    #pragma unroll
    for (int kc=0;kc<16;kc++) acc += tempP[((size_t)kc*NNODE + j0+j)*DD + d];
    #pragma unroll
    for (int t=0;t<TP;t++) {
        acc += su[j*16+t] * bf2f(B2[(size_t)(j0+j)*512 + t*32 + d]);   // u1 · B2[j,t,d]
        acc += sv[j*16+t] * bf2f(A2[(size_t)(j0+j)*512 + t*32 + d]);   // v2 · A2[j,t,d]
    }
    float r = fmaxf(acc, 0.2f*acc);   // leaky relu, LEAK=0.2
    size_t idx = (size_t)(j0+j)*DD + d;
    if (f32) ((float*)outv)[idx] = r;
    else     ((u16*)outv)[idx]   = f2bf(r);
}

// ---------------------------------------------------------------------------
extern "C" void kernel_launch(void* const* d_in, const int* in_sizes, int n_in,
                              void* d_out, int out_size, void* d_ws, size_t ws_size,
                              hipStream_t stream)
{
    (void)in_sizes; (void)n_in; (void)out_size; (void)ws_size;
    const void* x   = d_in[0];
    const void* adj = d_in[1];
    const void* W1  = d_in[2];
    const void* W2  = d_in[3];
    const void* W3  = d_in[4];

    char* ws = (char*)d_ws;
    u16*   adjP = (u16*)(ws + 0);              // 8 MB
    u16*   A1   = (u16*)(ws + 8388608);        // 512 KB
    u16*   B1   = (u16*)(ws + 8912896);
    u16*   A2   = (u16*)(ws + 9437184);
    u16*   B2   = (u16*)(ws + 9961472);
    float* Q    = (float*)(ws + 10485760);     // 64 KB
    float* QAd  = (float*)(ws + 10551296);     // 32 KB
    float* QB   = (float*)(ws + 10584064);     // 32 KB
    float* L1   = (float*)(ws + 10616832);     // 1 MB (becomes s1)
    float* L2T  = (float*)(ws + 11665408);     // 1 MB (becomes s2T)
    float* tempP= (float*)(ws + 12713984);     // 1 MB
    float* u1P  = (float*)(ws + 13762560);     // 512 KB
    float* v2P  = (float*)(ws + 14286848);     // 512 KB

    k_prep<<<512, 256, 0, stream>>>(x, W1, W2, W3, A1, B1, A2, B2, Q, QAd, QB);
    k_adjp<<<1024, 256, 0, stream>>>(adj, adjP);
    k_logits<<<dim3(32,32), 256, 0, stream>>>(adjP, A1, B1, Q, QAd, QB, L1, L2T);
    k_softmax<<<1024, 256, 0, stream>>>(L1, L2T);
    k_passc<<<512, 256, 0, stream>>>(adjP, A2, B2, L1, L2T, tempP, u1P, v2P);
    k_final<<<64, 256, 0, stream>>>(tempP, u1P, v2P, A2, B2, x, (u16*)d_out);
}

// Round 4
// 129.238 us; speedup vs baseline: 1.0666x; 1.0666x over previous
//
#include <hip/hip_runtime.h>
#include <hip/hip_bf16.h>

#define NNODE 512
#define CCH   16
#define TT    15
#define TP    16   // T+1, also padded t dimension
#define HH    32
#define DD    32

typedef unsigned short u16;
typedef unsigned int   u32;

__device__ __forceinline__ float bf2f(u16 v) {
    union { u32 u; float f; } x; x.u = ((u32)v) << 16; return x.f;
}
__device__ __forceinline__ u16 f2bf(float f) {
    union { float f; u32 u; } x; x.f = f;
    u32 u = x.u;
    u32 r = (u + 0x7FFFu + ((u >> 16) & 1u)) >> 16;
    return (u16)r;
}
__device__ __forceinline__ void unpack8(uint4 p, float* o) {
    o[0]=bf2f((u16)(p.x & 0xffffu)); o[1]=bf2f((u16)(p.x >> 16));
    o[2]=bf2f((u16)(p.y & 0xffffu)); o[3]=bf2f((u16)(p.y >> 16));
    o[4]=bf2f((u16)(p.z & 0xffffu)); o[5]=bf2f((u16)(p.z >> 16));
    o[6]=bf2f((u16)(p.w & 0xffffu)); o[7]=bf2f((u16)(p.w >> 16));
}

// ---------------------------------------------------------------------------
// Kernel 1 (merged): blocks 0..511 = prep (per-node precomputes);
//                    blocks 512..1535 = adjP build (coalesced via LDS).
// prep: A1[n,t,h]=sum_i x[n,i]W1[i,t,h]; B1 uses W1[C+i]; A2/B2 from W2;
//       Q=x@W3; QAd[n,t]=Q[n]·A1[n,t,:]; QB[n,t]=Q[n]·B1[n,t,:]
// adjP: [n][m][16] bf16, slot 15 = (n==m)?1:0 (folds diagonal exactly).
// ---------------------------------------------------------------------------
__global__ __launch_bounds__(256) void k_prep_adjp(
    const float* __restrict__ x, const float* __restrict__ W1,
    const float* __restrict__ W2, const float* __restrict__ W3,
    const float* __restrict__ adj,
    u16* __restrict__ A1, u16* __restrict__ B1,
    u16* __restrict__ A2, u16* __restrict__ B2,
    float* __restrict__ Q, float* __restrict__ QAd, float* __restrict__ QB,
    u16* __restrict__ adjP)
{
    int tid = threadIdx.x;
    if (blockIdx.x < 512) {
        // ---------------- prep ----------------
        int n = blockIdx.x;
        __shared__ alignas(16) float xs[CCH];
        __shared__ alignas(16) float A1row[512], B1row[512];
        __shared__ alignas(16) float Qs[HH];
        if (tid < CCH) xs[tid] = x[n*CCH + tid];
        __syncthreads();
        float xr[CCH];
        #pragma unroll
        for (int i=0;i<CCH;i++) xr[i]=xs[i];

        #pragma unroll
        for (int rep=0; rep<2; rep++) {
            int c = tid + rep*256;   // c = t*32 + h (or t*32 + d), 0..511
            float a1=0.f,b1=0.f,a2=0.f,b2=0.f;
            #pragma unroll
            for (int i=0;i<CCH;i++) {
                a1 += xr[i]*W1[i*512 + c];
                b1 += xr[i]*W1[(CCH+i)*512 + c];
                a2 += xr[i]*W2[i*512 + c];
                b2 += xr[i]*W2[(CCH+i)*512 + c];
            }
            A1[(size_t)n*512 + c]=f2bf(a1); B1[(size_t)n*512 + c]=f2bf(b1);
            A2[(size_t)n*512 + c]=f2bf(a2); B2[(size_t)n*512 + c]=f2bf(b2);
            A1row[c]=a1; B1row[c]=b1;
        }
        if (tid < HH) {
            float q=0.f;
            #pragma unroll
            for (int i=0;i<CCH;i++) q += xr[i]*W3[i*HH + tid];
            Qs[tid]=q; Q[(size_t)n*HH + tid]=q;
        }
        __syncthreads();
        if (tid < TP) {
            float qa=0.f, qb=0.f;
            #pragma unroll
            for (int h=0;h<HH;h++) { qa += Qs[h]*A1row[tid*HH+h]; qb += Qs[h]*B1row[tid*HH+h]; }
            QAd[(size_t)n*TP + tid]=qa; QB[(size_t)n*TP + tid]=qb;
        }
    } else {
        // ---------------- adjP ----------------
        __shared__ alignas(16) float sadj[256*TT];   // 15360 B slab
        int b2 = blockIdx.x - 512;                   // 0..1023
        int p0 = b2 * 256;                           // first pair this block
        const float* src = adj + (size_t)p0 * TT;
        #pragma unroll
        for (int k=0;k<TT;k++) sadj[tid + k*256] = src[tid + k*256];  // coalesced
        __syncthreads();
        int p = p0 + tid;
        int n = p >> 9, m = p & 511;
        u16 v[TP];
        #pragma unroll
        for (int t=0;t<TT;t++) v[t]=f2bf(sadj[tid*TT + t]);   // stride 15: <=2-way, free
        v[TT] = (n==m) ? (u16)0x3F80 : (u16)0;  // bf16 1.0 / 0.0
        uint4* d4 = (uint4*)(adjP + (size_t)p*TP);
        uint4 w0 = make_uint4((u32)v[0]|((u32)v[1]<<16), (u32)v[2]|((u32)v[3]<<16),
                              (u32)v[4]|((u32)v[5]<<16), (u32)v[6]|((u32)v[7]<<16));
        uint4 w1 = make_uint4((u32)v[8]|((u32)v[9]<<16), (u32)v[10]|((u32)v[11]<<16),
                              (u32)v[12]|((u32)v[13]<<16), (u32)v[14]|((u32)v[15]<<16));
        d4[0]=w0; d4[1]=w1;
    }
}

// ---------------------------------------------------------------------------
// Kernel 2: logits. Block = 16n x 16m tile. thread: ml=tid&15, nl=tid>>4.
// l1[n,m] = sum_t adjP[n,m,t]*(Qn·A1[m,t]) + adjP[m,n,t]*QB[n,t]
// l2[n,m] = sum_t adjP[n,m,t]*QAd[m,t]    + adjP[m,n,t]*(Qm·B1[n,t])
// L2 stored transposed (L2T[m][n]) so both softmaxes are row-wise.
// ---------------------------------------------------------------------------
#define LROW 520   // 512 + 8 bf16 pad: row stride 1040B (=65*16, keeps 16B align)
__global__ __launch_bounds__(256) void k_logits(
    const u16* __restrict__ adjP,
    const u16* __restrict__ A1, const u16* __restrict__ B1,
    const float* __restrict__ Q, const float* __restrict__ QAd, const float* __restrict__ QB,
    float* __restrict__ L1, float* __restrict__ L2T)
{
    const int m0 = blockIdx.x * 16;
    const int n0 = blockIdx.y * 16;
    const int tid = threadIdx.x;
    const int ml = tid & 15, nl = tid >> 4;

    __shared__ alignas(16) u16 smA1[16*LROW];
    __shared__ alignas(16) u16 smB1[16*LROW];
    __shared__ alignas(16) u16 smAdjMN[16*256];   // [m][n*16+t]
    __shared__ alignas(16) float smQAd[16*17];    // [m][t]
    __shared__ alignas(16) float smQB[16*17];     // [n][t]
    __shared__ alignas(16) float tr[16*17];

    {
        int row = tid >> 4, ch = tid & 15;
        const uint4* sA = (const uint4*)(A1 + (size_t)(m0+row)*512 + ch*32);
        uint4* dA = (uint4*)(smA1 + row*LROW + ch*32);
        dA[0]=sA[0]; dA[1]=sA[1]; dA[2]=sA[2]; dA[3]=sA[3];
        const uint4* sB = (const uint4*)(B1 + (size_t)(n0+row)*512 + ch*32);
        uint4* dB = (uint4*)(smB1 + row*LROW + ch*32);
        dB[0]=sB[0]; dB[1]=sB[1]; dB[2]=sB[2]; dB[3]=sB[3];
        // adjMN: rows m0..m0+15, cols n0..n0+15 (contiguous 512B per row)
        const uint4* sM = (const uint4*)(adjP + ((size_t)(m0+row)*512 + n0)*TP + ch*16);
        uint4* dM = (uint4*)(smAdjMN + row*256 + ch*16);
        dM[0]=sM[0]; dM[1]=sM[1];
        smQAd[row*17+ch] = QAd[(size_t)(m0+row)*TP + ch];
        smQB[row*17+ch]  = QB[(size_t)(n0+row)*TP + ch];
    }

    float qn[32], qm[32];
    #pragma unroll
    for (int h=0;h<32;h++) qn[h] = Q[(size_t)(n0+nl)*HH + h];
    #pragma unroll
    for (int h=0;h<32;h++) qm[h] = Q[(size_t)(m0+ml)*HH + h];

    // adjNM direct from global (coalesced 32B/lane)
    const uint4* pAdjA = (const uint4*)(adjP + ((size_t)(n0+nl)*512 + (m0+ml))*TP);
    uint4 aA0 = pAdjA[0], aA1 = pAdjA[1];
    float adjA[16];
    unpack8(aA0, adjA); unpack8(aA1, adjA+8);

    __syncthreads();

    const uint4* pAdjB = (const uint4*)(smAdjMN + ml*256 + nl*16);
    uint4 aB0 = pAdjB[0], aB1 = pAdjB[1];
    float adjB[16];
    unpack8(aB0, adjB); unpack8(aB1, adjB+8);

    float l1=0.f, l2=0.f;
    for (int t=0;t<TP;t++) {
        const uint4* pA = (const uint4*)(smA1 + ml*LROW + t*32);
        const uint4* pB = (const uint4*)(smB1 + nl*LROW + t*32);
        float dA=0.f, dB=0.f;
        #pragma unroll
        for (int q8=0;q8<4;q8++) {
            uint4 pa = pA[q8], pb = pB[q8];
            float av[8], bv[8];
            unpack8(pa, av); unpack8(pb, bv);
            #pragma unroll
            for (int h=0;h<8;h++) { dA += qn[q8*8+h]*av[h]; dB += qm[q8*8+h]*bv[h]; }
        }
        l1 = fmaf(adjA[t], dA, l1);
        l1 = fmaf(adjB[t], smQB[nl*17+t], l1);
        l2 = fmaf(adjA[t], smQAd[ml*17+t], l2);
        l2 = fmaf(adjB[t], dB, l2);
    }

    L1[(size_t)(n0+nl)*NNODE + m0+ml] = l1;     // coalesced (ml fast)
    tr[ml*17+nl] = l2;
    __syncthreads();
    {
        int r = tid >> 4, c = tid & 15;
        L2T[(size_t)(m0+r)*NNODE + n0+c] = tr[r*17+c];  // coalesced
    }
}

// ---------------------------------------------------------------------------
// Kernel 3: in-place row softmax. Blocks 0..511 -> rows of L1 (softmax over m);
// blocks 512..1023 -> rows of L2T (softmax over n, i.e. axis=0 of logits2).
// ---------------------------------------------------------------------------
__global__ __launch_bounds__(256) void k_softmax(float* __restrict__ L1, float* __restrict__ L2T)
{
    int b = blockIdx.x;
    float* row = (b < NNODE) ? (L1 + (size_t)b*NNODE) : (L2T + (size_t)(b-NNODE)*NNODE);
    int tid = threadIdx.x;
    float v0 = row[tid], v1 = row[tid+256];
    float m = fmaxf(v0, v1);
    #pragma unroll
    for (int o=32; o; o>>=1) m = fmaxf(m, __shfl_xor(m, o, 64));
    __shared__ alignas(16) float red[4];
    __shared__ alignas(16) float red2[4];
    int lane = tid & 63, wv = tid >> 6;
    if (!lane) red[wv] = m;
    __syncthreads();
    m = fmaxf(fmaxf(red[0],red[1]), fmaxf(red[2],red[3]));
    float e0 = __expf(v0 - m), e1 = __expf(v1 - m);
    float s = e0 + e1;
    #pragma unroll
    for (int o=32; o; o>>=1) s += __shfl_xor(s, o, 64);
    if (!lane) red2[wv] = s;
    __syncthreads();
    s = red2[0]+red2[1]+red2[2]+red2[3];
    float inv = 1.0f / s;
    row[tid] = e0*inv; row[tid+256] = e1*inv;
}

// ---------------------------------------------------------------------------
// Kernel 4: temp partials. Block = (j-tile of 16) x (k-chunk of 32).
// acc[j,d] += s1[j,k]*adjP[j,k,t]*A2[k,t,d] + s2T[j,k]*adjP[j,k,t]*B2[k,t,d]
// u1[j,t]  += s1[j,k]*adjP[k,j,t];  v2[j,t] += s2T[j,k]*adjP[k,j,t]
// thread: jl=tid>>4, c=tid&15 -> d pair (2c,2c+1); u/v slot t=c.
// ---------------------------------------------------------------------------
__global__ __launch_bounds__(256) void k_passc(
    const u16* __restrict__ adjP, const u16* __restrict__ A2, const u16* __restrict__ B2,
    const float* __restrict__ S1, const float* __restrict__ S2T,
    float* __restrict__ tempP, float* __restrict__ u1P, float* __restrict__ v2P)
{
    const int jt = blockIdx.x >> 4;
    const int kc = blockIdx.x & 15;
    const int j0 = jt * 16;
    const int k0 = kc * 32;
    const int tid = threadIdx.x;
    const int jl = tid >> 4, c = tid & 15;

    __shared__ alignas(16) u16 sA2[8*512];
    __shared__ alignas(16) u16 sB2[8*512];
    __shared__ alignas(16) u16 sAJK[16*128];  // [j][kk*16+t]
    __shared__ alignas(16) u16 sAKJ[8*256];   // [kk][j*16+t]
    __shared__ alignas(16) float sS1[16*9];
    __shared__ alignas(16) float sS2[16*9];

    float acc0=0.f, acc1=0.f, uacc=0.f, vacc=0.f;

    for (int kb=0; kb<4; kb++) {
        int kbase = k0 + kb*8;
        __syncthreads();
        {
            int row = tid >> 5, ch = tid & 31;   // 8 rows x 32 chunks of 16 u16
            const uint4* sa = (const uint4*)(A2 + (size_t)(kbase+row)*512 + ch*16);
            uint4* da = (uint4*)(sA2 + row*512 + ch*16);
            da[0]=sa[0]; da[1]=sa[1];
            const uint4* sb = (const uint4*)(B2 + (size_t)(kbase+row)*512 + ch*16);
            uint4* db = (uint4*)(sB2 + row*512 + ch*16);
            db[0]=sb[0]; db[1]=sb[1];
            // adjKJ: rows kbase..+7, cols j0..j0+15 : 256 u16 per row
            const uint4* sk = (const uint4*)(adjP + ((size_t)(kbase+row)*512 + j0)*TP + ch*8);
            uint4* dk = (uint4*)(sAKJ + row*256 + ch*8);
            dk[0]=sk[0];
        }
        {
            int j = tid >> 4, ch = tid & 15;     // 16 rows x 16 chunks of 8 u16
            const uint4* sj = (const uint4*)(adjP + ((size_t)(j0+j)*512 + kbase)*TP + ch*8);
            uint4* dj = (uint4*)(sAJK + j*128 + ch*8);
            dj[0]=sj[0];
        }
        if (tid < 128) {
            int j = tid >> 3, kk = tid & 7;
            sS1[j*9+kk] = S1[(size_t)(j0+j)*NNODE + kbase+kk];
            sS2[j*9+kk] = S2T[(size_t)(j0+j)*NNODE + kbase+kk];
        }
        __syncthreads();

        for (int kk=0; kk<8; kk++) {
            float s1v = sS1[jl*9+kk];
            float s2v = sS2[jl*9+kk];
            const uint4* pj = (const uint4*)(sAJK + jl*128 + kk*16);
            float at[16];
            unpack8(pj[0], at); unpack8(pj[1], at+8);
            #pragma unroll
            for (int t=0;t<TP;t++) {
                u32 pa = *(const u32*)(sA2 + kk*512 + t*32 + 2*c);
                u32 pb = *(const u32*)(sB2 + kk*512 + t*32 + 2*c);
                float w1 = s1v*at[t], w2 = s2v*at[t];
                acc0 += w1*bf2f((u16)(pa & 0xffffu)) + w2*bf2f((u16)(pb & 0xffffu));
                acc1 += w1*bf2f((u16)(pa >> 16))     + w2*bf2f((u16)(pb >> 16));
            }
            float akj = bf2f(sAKJ[kk*256 + jl*16 + c]);
            uacc += s1v*akj;
            vacc += s2v*akj;
        }
    }
    float2 o; o.x = acc0; o.y = acc1;
    *(float2*)(tempP + ((size_t)kc*NNODE + j0+jl)*DD + 2*c) = o;
    u1P[((size_t)kc*NNODE + j0+jl)*TP + c] = uacc;
    v2P[((size_t)kc*NNODE + j0+jl)*TP + c] = vacc;
}

// ---------------------------------------------------------------------------
// Kernel 5: reduce partials, add self terms, leaky-ReLU, write f32 out.
// ---------------------------------------------------------------------------
__global__ __launch_bounds__(256) void k_final(
    const float* __restrict__ tempP, const float* __restrict__ u1P, const float* __restrict__ v2P,
    const u16* __restrict__ A2, const u16* __restrict__ B2, float* __restrict__ out)
{
    int j0 = blockIdx.x * 8;
    int tid = threadIdx.x;
    __shared__ alignas(16) float su[8*16];
    __shared__ alignas(16) float sv[8*16];
    if (tid < 128) {
        int j = tid >> 4, t = tid & 15;
        float us=0.f, vs=0.f;
        #pragma unroll
        for (int kc=0;kc<16;kc++) {
            us += u1P[((size_t)kc*NNODE + j0+j)*TP + t];
            vs += v2P[((size_t)kc*NNODE + j0+j)*TP + t];
        }
        su[j*16+t]=us; sv[j*16+t]=vs;
    }
    __syncthreads();
    int j = tid >> 5, d = tid & 31;
    float acc = 0.f;
    #pragma unroll
    for (int kc=0;kc<16;kc++) acc += tempP[((size_t)kc*NNODE + j0+j)*DD + d];
    #pragma unroll
    for (int t=0;t<TP;t++) {
        acc += su[j*16+t] * bf2f(B2[(size_t)(j0+j)*512 + t*32 + d]);   // u1 · B2[j,t,d]
        acc += sv[j*16+t] * bf2f(A2[(size_t)(j0+j)*512 + t*32 + d]);   // v2 · A2[j,t,d]
    }
    float r = fmaxf(acc, 0.2f*acc);   // leaky relu, LEAK=0.2
    out[(size_t)(j0+j)*DD + d] = r;
}

// ---------------------------------------------------------------------------
extern "C" void kernel_launch(void* const* d_in, const int* in_sizes, int n_in,
                              void* d_out, int out_size, void* d_ws, size_t ws_size,
                              hipStream_t stream)
{
    (void)in_sizes; (void)n_in; (void)out_size; (void)ws_size;
    const float* x   = (const float*)d_in[0];
    const float* adj = (const float*)d_in[1];
    const float* W1  = (const float*)d_in[2];
    const float* W2  = (const float*)d_in[3];
    const float* W3  = (const float*)d_in[4];

    char* ws = (char*)d_ws;
    u16*   adjP = (u16*)(ws + 0);              // 8 MB
    u16*   A1   = (u16*)(ws + 8388608);        // 512 KB
    u16*   B1   = (u16*)(ws + 8912896);
    u16*   A2   = (u16*)(ws + 9437184);
    u16*   B2   = (u16*)(ws + 9961472);
    float* Q    = (float*)(ws + 10485760);     // 64 KB
    float* QAd  = (float*)(ws + 10551296);     // 32 KB
    float* QB   = (float*)(ws + 10584064);     // 32 KB
    float* L1   = (float*)(ws + 10616832);     // 1 MB (becomes s1)
    float* L2T  = (float*)(ws + 11665408);     // 1 MB (becomes s2T)
    float* tempP= (float*)(ws + 12713984);     // 1 MB
    float* u1P  = (float*)(ws + 13762560);     // 512 KB
    float* v2P  = (float*)(ws + 14286848);     // 512 KB

    k_prep_adjp<<<1536, 256, 0, stream>>>(x, W1, W2, W3, adj,
                                          A1, B1, A2, B2, Q, QAd, QB, adjP);
    k_logits<<<dim3(32,32), 256, 0, stream>>>(adjP, A1, B1, Q, QAd, QB, L1, L2T);
    k_softmax<<<1024, 256, 0, stream>>>(L1, L2T);
    k_passc<<<512, 256, 0, stream>>>(adjP, A2, B2, L1, L2T, tempP, u1P, v2P);
    k_final<<<64, 256, 0, stream>>>(tempP, u1P, v2P, A2, B2, (float*)d_out);
}

// Round 5
// 120.614 us; speedup vs baseline: 1.1429x; 1.0715x over previous
//
#include <hip/hip_runtime.h>
#include <hip/hip_bf16.h>

#define NNODE 512
#define CCH   16
#define TT    15
#define TP    16
#define HH    32
#define DD    32

typedef unsigned short u16;
typedef unsigned int   u32;
typedef short bf8 __attribute__((ext_vector_type(8)));   // 8 bf16 = 4 VGPR (MFMA A/B frag)
typedef float f4  __attribute__((ext_vector_type(4)));   // MFMA C/D frag

__device__ __forceinline__ float bf2f(u16 v) {
    union { u32 u; float f; } x; x.u = ((u32)v) << 16; return x.f;
}
__device__ __forceinline__ u16 f2bf(float f) {
    union { float f; u32 u; } x; x.f = f;
    u32 u = x.u;
    return (u16)((u + 0x7FFFu + ((u >> 16) & 1u)) >> 16);
}
__device__ __forceinline__ void unpack8(uint4 p, float* o) {
    o[0]=bf2f((u16)(p.x & 0xffffu)); o[1]=bf2f((u16)(p.x >> 16));
    o[2]=bf2f((u16)(p.y & 0xffffu)); o[3]=bf2f((u16)(p.y >> 16));
    o[4]=bf2f((u16)(p.z & 0xffffu)); o[5]=bf2f((u16)(p.z >> 16));
    o[6]=bf2f((u16)(p.w & 0xffffu)); o[7]=bf2f((u16)(p.w >> 16));
}
__device__ __forceinline__ uint4 pack8(const u16* v) {
    return make_uint4((u32)v[0]|((u32)v[1]<<16), (u32)v[2]|((u32)v[3]<<16),
                      (u32)v[4]|((u32)v[5]<<16), (u32)v[6]|((u32)v[7]<<16));
}

// ---------------------------------------------------------------------------
// K1: blocks 0..511: per-node prep: A1/B1/A2/B2 bf16 [n][t*32+c], Qb bf16,
//     QAd[n,t]=Q·A1[n,t,:], QB[n,t]=Q·B1[n,t,:] (f32).
//     blocks 512..767: 32x32 adjacency tiles -> adjP[n][m*16+t] AND
//     adjPT[m][n*16+t] (both bf16, diag folded into t=15). All IO coalesced.
// ---------------------------------------------------------------------------
__global__ __launch_bounds__(256) void k_prep_adjp(
    const float* __restrict__ x, const float* __restrict__ W1,
    const float* __restrict__ W2, const float* __restrict__ W3,
    const float* __restrict__ adj,
    u16* __restrict__ A1, u16* __restrict__ B1,
    u16* __restrict__ A2, u16* __restrict__ B2,
    u16* __restrict__ Qb, float* __restrict__ QAd, float* __restrict__ QB,
    u16* __restrict__ adjP, u16* __restrict__ adjPT)
{
    int tid = threadIdx.x;
    if (blockIdx.x < 512) {
        int n = blockIdx.x;
        __shared__ alignas(16) float xs[CCH];
        __shared__ alignas(16) float A1row[512], B1row[512];
        __shared__ alignas(16) float Qs[HH];
        if (tid < CCH) xs[tid] = x[n*CCH + tid];
        __syncthreads();
        float xr[CCH];
        #pragma unroll
        for (int i=0;i<CCH;i++) xr[i]=xs[i];
        #pragma unroll
        for (int rep=0; rep<2; rep++) {
            int c = tid + rep*256;
            float a1=0.f,b1=0.f,a2=0.f,b2=0.f;
            #pragma unroll
            for (int i=0;i<CCH;i++) {
                a1 += xr[i]*W1[i*512 + c];
                b1 += xr[i]*W1[(CCH+i)*512 + c];
                a2 += xr[i]*W2[i*512 + c];
                b2 += xr[i]*W2[(CCH+i)*512 + c];
            }
            A1[(size_t)n*512 + c]=f2bf(a1); B1[(size_t)n*512 + c]=f2bf(b1);
            A2[(size_t)n*512 + c]=f2bf(a2); B2[(size_t)n*512 + c]=f2bf(b2);
            A1row[c]=a1; B1row[c]=b1;
        }
        if (tid < HH) {
            float q=0.f;
            #pragma unroll
            for (int i=0;i<CCH;i++) q += xr[i]*W3[i*HH + tid];
            Qs[tid]=q; Qb[(size_t)n*HH + tid]=f2bf(q);
        }
        __syncthreads();
        if (tid < TP) {
            float qa=0.f, qb=0.f;
            #pragma unroll
            for (int h=0;h<HH;h++) { qa += Qs[h]*A1row[tid*HH+h]; qb += Qs[h]*B1row[tid*HH+h]; }
            QAd[(size_t)n*TP + tid]=qa; QB[(size_t)n*TP + tid]=qb;
        }
    } else {
        int b = blockIdx.x - 512;            // 0..255
        int n0 = (b >> 4) * 32, m0 = (b & 15) * 32;
        __shared__ alignas(16) u16 s[32*520];  // [nl][ml*16+t], stride 520 (1040B=65*16)
        #pragma unroll
        for (int i = 0; i < 60; i++) {
            int e = tid + i*256;             // 0..15359 = 32 nl * 480
            int nl = e / 480; int rem = e - nl*480;
            int ml = rem / 15; int t = rem - ml*15;
            float v = adj[((size_t)(n0+nl)*512 + (m0+ml))*TT + t];
            s[nl*520 + ml*16 + t] = f2bf(v);
        }
        #pragma unroll
        for (int i = 0; i < 4; i++) {
            int e = tid + i*256; int nl = e >> 5, ml = e & 31;
            s[nl*520 + ml*16 + 15] = ((n0+nl) == (m0+ml)) ? (u16)0x3F80 : (u16)0;
        }
        __syncthreads();
        #pragma unroll
        for (int i = 0; i < 8; i++) {        // adjP: 32 rows x 1KB
            int c = tid + i*256;
            int nl = c >> 6, off = (c & 63) * 8;
            uint4 vv = *(const uint4*)(s + nl*520 + off);
            *(uint4*)(adjP + (size_t)(n0+nl)*8192 + m0*16 + off) = vv;
        }
        #pragma unroll
        for (int i = 0; i < 8; i++) {        // adjPT: 32 rows x 1KB (transposed)
            int c = tid + i*256;
            int ml = c >> 6, nlh = c & 63, nl = nlh >> 1, half = nlh & 1;
            uint4 vv = *(const uint4*)(s + nl*520 + ml*16 + half*8);
            *(uint4*)(adjPT + (size_t)(m0+ml)*8192 + (n0+nl)*16 + half*8) = vv;
        }
    }
}

// ---------------------------------------------------------------------------
// K2: MFMA GEMMs G[n][(m,t)] = Qb·A1 and H[m][(n,t)] = Qb·B1 (K=32, one
//     mfma per 16x16 tile; 1 tile/wave). Blocks >= 8192: transpose A2->A2T,
//     B2->B2T into [d][(k,t)] layout for gemm2's B-fragments.
// ---------------------------------------------------------------------------
__global__ __launch_bounds__(256) void k_gemmGH(
    const u16* __restrict__ Qb, const u16* __restrict__ A1, const u16* __restrict__ B1,
    const u16* __restrict__ A2, const u16* __restrict__ B2,
    u16* __restrict__ G, u16* __restrict__ H,
    u16* __restrict__ A2T, u16* __restrict__ B2T)
{
    int tid = threadIdx.x;
    int bx = blockIdx.x;
    if (bx < 8192) {
        int wv = tid >> 6, lane = tid & 63;
        int l15 = lane & 15, quad = lane >> 4;
        bool isH = bx >= 4096;
        int w = ((isH ? bx - 4096 : bx) << 2) + wv;   // 0..16383
        int rt = w >> 9;            // row tile (n for G, m for H)
        int ct = w & 511;           // col tile = node index of B-side row
        const u16* Bsrc = isH ? B1 : A1;
        u16* Dst = isH ? H : G;
        // A-frag: rows = Qb, A[r=lane&15][k=quad*8+i]
        bf8 afrag = *(const bf8*)(Qb + (size_t)(rt*16 + l15)*32 + quad*8);
        // B-frag: col = t (lane&15), B[k=h][t] = A1[ct][t*32+h]
        bf8 bfrag = *(const bf8*)(Bsrc + (size_t)ct*512 + l15*32 + quad*8);
        f4 acc = {0.f, 0.f, 0.f, 0.f};
        acc = __builtin_amdgcn_mfma_f32_16x16x32_bf16(afrag, bfrag, acc, 0, 0, 0);
        #pragma unroll
        for (int r = 0; r < 4; r++)
            Dst[(size_t)(rt*16 + quad*4 + r)*8192 + ct*16 + l15] = f2bf(acc[r]);
    } else {
        int b = bx - 8192;          // 0..127
        bool isB = b >= 64;
        const u16* src = isB ? B2 : A2;
        u16* dst = isB ? B2T : A2T;
        int idx = ((b & 63) << 8) + tid;   // 0..16383 = 32 d * 512 k
        int d = idx >> 9, k = idx & 511;
        u16 tmp[16];
        #pragma unroll
        for (int t = 0; t < 16; t++) tmp[t] = src[(size_t)k*512 + t*32 + d];
        uint4* o = (uint4*)(dst + (size_t)d*8192 + k*16);
        o[0] = pack8(tmp); o[1] = pack8(tmp+8);
    }
}

// ---------------------------------------------------------------------------
// K3: logits combine (pure elementwise, all reads row-major):
// l1[n,m] = sum_t adjP[n,m,t]*G[n,(m,t)] + adjPT[n,(m,t)]*QB[n,t]
// l2[n,m] = sum_t adjP[n,m,t]*QAd[m,t]   + adjPT[n,(m,t)]*H[m,(n,t)]
// L2 stored transposed via LDS tile.
// ---------------------------------------------------------------------------
__global__ __launch_bounds__(256) void k_combine(
    const u16* __restrict__ adjP, const u16* __restrict__ adjPT,
    const u16* __restrict__ G, const u16* __restrict__ H,
    const float* __restrict__ QAd, const float* __restrict__ QB,
    float* __restrict__ L1, float* __restrict__ L2T)
{
    int m0 = blockIdx.x*16, n0 = blockIdx.y*16;
    int tid = threadIdx.x, ml = tid & 15, nl = tid >> 4;
    int n = n0 + nl, m = m0 + ml;
    __shared__ alignas(16) float tr[16*17];
    const uint4* pA = (const uint4*)(adjP  + (size_t)n*8192 + m*16);
    const uint4* pT = (const uint4*)(adjPT + (size_t)n*8192 + m*16);
    const uint4* pG = (const uint4*)(G + (size_t)n*8192 + m*16);
    const uint4* pH = (const uint4*)(H + (size_t)m*8192 + n*16);
    float a[16], at[16], g[16], h[16], qa[16], qb[16];
    unpack8(pA[0], a);  unpack8(pA[1], a+8);
    unpack8(pT[0], at); unpack8(pT[1], at+8);
    unpack8(pG[0], g);  unpack8(pG[1], g+8);
    unpack8(pH[0], h);  unpack8(pH[1], h+8);
    #pragma unroll
    for (int q4 = 0; q4 < 4; q4++) {
        float4 va = *(const float4*)(QAd + m*16 + q4*4);
        float4 vb = *(const float4*)(QB  + n*16 + q4*4);
        qa[q4*4+0]=va.x; qa[q4*4+1]=va.y; qa[q4*4+2]=va.z; qa[q4*4+3]=va.w;
        qb[q4*4+0]=vb.x; qb[q4*4+1]=vb.y; qb[q4*4+2]=vb.z; qb[q4*4+3]=vb.w;
    }
    float l1 = 0.f, l2 = 0.f;
    #pragma unroll
    for (int t = 0; t < 16; t++) {
        l1 = fmaf(a[t], g[t],  fmaf(at[t], qb[t], l1));
        l2 = fmaf(a[t], qa[t], fmaf(at[t], h[t],  l2));
    }
    L1[(size_t)n*NNODE + m] = l1;
    tr[ml*17+nl] = l2;
    __syncthreads();
    int r = tid >> 4, c = tid & 15;
    L2T[(size_t)(m0+r)*NNODE + n0+c] = tr[r*17+c];
}

// ---------------------------------------------------------------------------
// K4: softmax over a 512-row + FUSED W-build and u/v reduction.
// blocks 0..511 (row j of L1 -> s1):  W1c[j][(k,t)] = s1[j,k]*adjP[j][(k,t)]
//                                     u1[j,t] = sum_k s1[j,k]*adjPT[j][(k,t)]
// blocks 512..1023 (row j of L2T -> s2T): same with W2c / v2.
// s rows are never written back (consumed here only).
// ---------------------------------------------------------------------------
__global__ __launch_bounds__(256) void k_softmax_w(
    const float* __restrict__ L1, const float* __restrict__ L2T,
    const u16* __restrict__ adjP, const u16* __restrict__ adjPT,
    u16* __restrict__ W1c, u16* __restrict__ W2c,
    float* __restrict__ u1, float* __restrict__ v2)
{
    int b = blockIdx.x, tid = threadIdx.x;
    bool first = b < NNODE;
    int j = first ? b : b - NNODE;
    const float* row = first ? (L1 + (size_t)j*NNODE) : (L2T + (size_t)j*NNODE);
    u16* W  = (first ? W1c : W2c) + (size_t)j*8192;
    float* uv = (first ? u1 : v2) + (size_t)j*TP;

    float v0 = row[tid], v1 = row[tid+256];
    float mx = fmaxf(v0, v1);
    #pragma unroll
    for (int o=32; o; o>>=1) mx = fmaxf(mx, __shfl_xor(mx, o, 64));
    __shared__ alignas(16) float red[4], red2[4], ur[4][16];
    int lane = tid & 63, wv = tid >> 6;
    if (!lane) red[wv] = mx;
    __syncthreads();
    mx = fmaxf(fmaxf(red[0],red[1]), fmaxf(red[2],red[3]));
    float e0 = __expf(v0 - mx), e1 = __expf(v1 - mx);
    float sm = e0 + e1;
    #pragma unroll
    for (int o=32; o; o>>=1) sm += __shfl_xor(sm, o, 64);
    if (!lane) red2[wv] = sm;
    __syncthreads();
    float inv = 1.0f / (red2[0]+red2[1]+red2[2]+red2[3]);
    float sa = e0*inv, sb = e1*inv;

    const u16* ap = adjP  + (size_t)j*8192;
    const u16* tp = adjPT + (size_t)j*8192;
    float u[16];
    #pragma unroll
    for (int t=0;t<16;t++) u[t]=0.f;
    #pragma unroll
    for (int half = 0; half < 2; half++) {
        int k = tid + half*256;
        float sv = half ? sb : sa;
        const uint4* p = (const uint4*)(ap + k*16);
        float av[16]; unpack8(p[0], av); unpack8(p[1], av+8);
        u16 o16[16];
        #pragma unroll
        for (int t=0;t<16;t++) o16[t] = f2bf(sv*av[t]);
        uint4* wp = (uint4*)(W + k*16);
        wp[0] = pack8(o16); wp[1] = pack8(o16+8);
        const uint4* q = (const uint4*)(tp + k*16);
        float tv[16]; unpack8(q[0], tv); unpack8(q[1], tv+8);
        #pragma unroll
        for (int t=0;t<16;t++) u[t] = fmaf(sv, tv[t], u[t]);
    }
    #pragma unroll
    for (int t=0;t<16;t++) {
        #pragma unroll
        for (int o=32; o; o>>=1) u[t] += __shfl_xor(u[t], o, 64);
    }
    if (!lane) {
        #pragma unroll
        for (int t=0;t<16;t++) ur[wv][t] = u[t];
    }
    __syncthreads();
    if (tid < 16) uv[tid] = ur[0][tid]+ur[1][tid]+ur[2][tid]+ur[3][tid];
}

// ---------------------------------------------------------------------------
// K5: MFMA GEMM temp[j,d] = W1c[j,:]·A2T[d,:] + W2c[j,:]·B2T[d,:]
// (M=512, N=32, K=8192 split into 16 k-chunks; partials to tempP)
// ---------------------------------------------------------------------------
__global__ __launch_bounds__(256) void k_gemm2(
    const u16* __restrict__ W1c, const u16* __restrict__ W2c,
    const u16* __restrict__ A2T, const u16* __restrict__ B2T,
    float* __restrict__ tempP)
{
    int tid = threadIdx.x;
    int wv = tid >> 6, lane = tid & 63, l15 = lane & 15, quad = lane >> 4;
    int w = blockIdx.x*4 + wv;             // 0..1023
    int kc = w & 15, dt = (w >> 4) & 1, jt = w >> 5;
    size_t aRow = (size_t)(jt*16 + l15)*8192;
    size_t bRow = (size_t)(dt*16 + l15)*8192;
    int kt0 = kc*512 + quad*8;
    f4 acc = {0.f, 0.f, 0.f, 0.f};
    #pragma unroll
    for (int s = 0; s < 16; s++) {
        int kt = kt0 + s*32;
        bf8 aw1 = *(const bf8*)(W1c + aRow + kt);
        bf8 ba2 = *(const bf8*)(A2T + bRow + kt);
        acc = __builtin_amdgcn_mfma_f32_16x16x32_bf16(aw1, ba2, acc, 0, 0, 0);
        bf8 aw2 = *(const bf8*)(W2c + aRow + kt);
        bf8 bb2 = *(const bf8*)(B2T + bRow + kt);
        acc = __builtin_amdgcn_mfma_f32_16x16x32_bf16(aw2, bb2, acc, 0, 0, 0);
    }
    #pragma unroll
    for (int r = 0; r < 4; r++)
        tempP[((size_t)kc*NNODE + jt*16 + quad*4 + r)*DD + dt*16 + l15] = acc[r];
}

// ---------------------------------------------------------------------------
// K6: reduce k-chunk partials, add self terms (u1·B2 + v2·A2), lrelu, f32 out.
// ---------------------------------------------------------------------------
__global__ __launch_bounds__(256) void k_final(
    const float* __restrict__ tempP, const float* __restrict__ u1, const float* __restrict__ v2,
    const u16* __restrict__ A2, const u16* __restrict__ B2, float* __restrict__ out)
{
    int j0 = blockIdx.x * 8;
    int tid = threadIdx.x;
    int j = tid >> 5, d = tid & 31;
    int jj = j0 + j;
    float acc = 0.f;
    #pragma unroll
    for (int kc=0;kc<16;kc++) acc += tempP[((size_t)kc*NNODE + jj)*DD + d];
    #pragma unroll
    for (int t=0;t<TP;t++) {
        acc += u1[(size_t)jj*TP + t] * bf2f(B2[(size_t)jj*512 + t*32 + d]);
        acc += v2[(size_t)jj*TP + t] * bf2f(A2[(size_t)jj*512 + t*32 + d]);
    }
    out[(size_t)jj*DD + d] = fmaxf(acc, 0.2f*acc);
}

// ---------------------------------------------------------------------------
extern "C" void kernel_launch(void* const* d_in, const int* in_sizes, int n_in,
                              void* d_out, int out_size, void* d_ws, size_t ws_size,
                              hipStream_t stream)
{
    (void)in_sizes; (void)n_in; (void)out_size; (void)ws_size;
    const float* x   = (const float*)d_in[0];
    const float* adj = (const float*)d_in[1];
    const float* W1  = (const float*)d_in[2];
    const float* W2  = (const float*)d_in[3];
    const float* W3  = (const float*)d_in[4];

    char* ws = (char*)d_ws;
    u16*   adjP = (u16*)(ws);                   // 8 MB
    u16*   adjPT= (u16*)(ws + 0x800000);        // 8 MB
    u16*   G    = (u16*)(ws + 0x1000000);       // 8 MB
    u16*   H    = (u16*)(ws + 0x1800000);       // 8 MB
    u16*   W1c  = (u16*)(ws + 0x2000000);       // 8 MB
    u16*   W2c  = (u16*)(ws + 0x2800000);       // 8 MB
    u16*   A1   = (u16*)(ws + 0x3000000);       // 512 KB each
    u16*   B1   = (u16*)(ws + 0x3080000);
    u16*   A2   = (u16*)(ws + 0x3100000);
    u16*   B2   = (u16*)(ws + 0x3180000);
    u16*   A2T  = (u16*)(ws + 0x3200000);
    u16*   B2T  = (u16*)(ws + 0x3280000);
    u16*   Qb   = (u16*)(ws + 0x3300000);       // 32 KB
    float* QAd  = (float*)(ws + 0x3310000);     // 32 KB
    float* QB   = (float*)(ws + 0x3320000);     // 32 KB
    float* u1   = (float*)(ws + 0x3330000);     // 32 KB
    float* v2   = (float*)(ws + 0x3340000);     // 32 KB
    float* L1   = (float*)(ws + 0x3400000);     // 1 MB
    float* L2T  = (float*)(ws + 0x3500000);     // 1 MB
    float* tempP= (float*)(ws + 0x3600000);     // 1 MB

    k_prep_adjp<<<768, 256, 0, stream>>>(x, W1, W2, W3, adj,
                                         A1, B1, A2, B2, Qb, QAd, QB, adjP, adjPT);
    k_gemmGH<<<8320, 256, 0, stream>>>(Qb, A1, B1, A2, B2, G, H, A2T, B2T);
    k_combine<<<dim3(32,32), 256, 0, stream>>>(adjP, adjPT, G, H, QAd, QB, L1, L2T);
    k_softmax_w<<<1024, 256, 0, stream>>>(L1, L2T, adjP, adjPT, W1c, W2c, u1, v2);
    k_gemm2<<<256, 256, 0, stream>>>(W1c, W2c, A2T, B2T, tempP);
    k_final<<<64, 256, 0, stream>>>(tempP, u1, v2, A2, B2, (float*)d_out);
}

// Round 6
// 115.539 us; speedup vs baseline: 1.1931x; 1.0439x over previous
//
#include <hip/hip_runtime.h>
#include <hip/hip_bf16.h>

#define NNODE 512
#define CCH   16
#define TT    15
#define TP    16
#define HH    32
#define DD    32

typedef unsigned short u16;
typedef unsigned int   u32;
typedef short bf8 __attribute__((ext_vector_type(8)));   // 8 bf16 = 4 VGPR (MFMA A/B frag)
typedef float f4  __attribute__((ext_vector_type(4)));   // MFMA C/D frag

__device__ __forceinline__ float bf2f(u16 v) {
    union { u32 u; float f; } x; x.u = ((u32)v) << 16; return x.f;
}
__device__ __forceinline__ u16 f2bf(float f) {
    union { float f; u32 u; } x; x.f = f;
    u32 u = x.u;
    return (u16)((u + 0x7FFFu + ((u >> 16) & 1u)) >> 16);
}
__device__ __forceinline__ void unpack8(uint4 p, float* o) {
    o[0]=bf2f((u16)(p.x & 0xffffu)); o[1]=bf2f((u16)(p.x >> 16));
    o[2]=bf2f((u16)(p.y & 0xffffu)); o[3]=bf2f((u16)(p.y >> 16));
    o[4]=bf2f((u16)(p.z & 0xffffu)); o[5]=bf2f((u16)(p.z >> 16));
    o[6]=bf2f((u16)(p.w & 0xffffu)); o[7]=bf2f((u16)(p.w >> 16));
}
__device__ __forceinline__ uint4 pack8(const u16* v) {
    return make_uint4((u32)v[0]|((u32)v[1]<<16), (u32)v[2]|((u32)v[3]<<16),
                      (u32)v[4]|((u32)v[5]<<16), (u32)v[6]|((u32)v[7]<<16));
}

// ---------------------------------------------------------------------------
// K1: blocks 0..511: per-node prep: A1/B1/A2/B2 bf16 [n][t*32+c], Qb bf16,
//     QAd[n,t]=Q·A1[n,t,:], QB[n,t]=Q·B1[n,t,:] (f32), plus transposed
//     A2T/B2T [d][(k=n)*16+t] written via LDS (coalesced u32 segments).
//     blocks 512..767: 32x32 adjacency tiles -> adjP[n][m*16+t] AND
//     adjPT[m][n*16+t] (both bf16, diag folded into t=15).
// ---------------------------------------------------------------------------
__global__ __launch_bounds__(256) void k_prep_adjp(
    const float* __restrict__ x, const float* __restrict__ W1,
    const float* __restrict__ W2, const float* __restrict__ W3,
    const float* __restrict__ adj,
    u16* __restrict__ A1, u16* __restrict__ B1,
    u16* __restrict__ A2, u16* __restrict__ B2,
    u16* __restrict__ A2T, u16* __restrict__ B2T,
    u16* __restrict__ Qb, float* __restrict__ QAd, float* __restrict__ QB,
    u16* __restrict__ adjP, u16* __restrict__ adjPT)
{
    int tid = threadIdx.x;
    if (blockIdx.x < 512) {
        int n = blockIdx.x;
        __shared__ alignas(16) float xs[CCH];
        __shared__ alignas(16) float A1row[512], B1row[512];
        __shared__ alignas(16) float A2row[512], B2row[512];
        __shared__ alignas(16) float Qs[HH];
        if (tid < CCH) xs[tid] = x[n*CCH + tid];
        __syncthreads();
        float xr[CCH];
        #pragma unroll
        for (int i=0;i<CCH;i++) xr[i]=xs[i];
        #pragma unroll
        for (int rep=0; rep<2; rep++) {
            int c = tid + rep*256;
            float a1=0.f,b1=0.f,a2=0.f,b2=0.f;
            #pragma unroll
            for (int i=0;i<CCH;i++) {
                a1 += xr[i]*W1[i*512 + c];
                b1 += xr[i]*W1[(CCH+i)*512 + c];
                a2 += xr[i]*W2[i*512 + c];
                b2 += xr[i]*W2[(CCH+i)*512 + c];
            }
            A1[(size_t)n*512 + c]=f2bf(a1); B1[(size_t)n*512 + c]=f2bf(b1);
            A2[(size_t)n*512 + c]=f2bf(a2); B2[(size_t)n*512 + c]=f2bf(b2);
            A1row[c]=a1; B1row[c]=b1; A2row[c]=a2; B2row[c]=b2;
        }
        if (tid < HH) {
            float q=0.f;
            #pragma unroll
            for (int i=0;i<CCH;i++) q += xr[i]*W3[i*HH + tid];
            Qs[tid]=q; Qb[(size_t)n*HH + tid]=f2bf(q);
        }
        __syncthreads();
        if (tid < TP) {
            float qa=0.f, qb=0.f;
            #pragma unroll
            for (int h=0;h<HH;h++) { qa += Qs[h]*A1row[tid*HH+h]; qb += Qs[h]*B1row[tid*HH+h]; }
            QAd[(size_t)n*TP + tid]=qa; QB[(size_t)n*TP + tid]=qb;
        }
        {   // A2T/B2T: [d][n*16+t]; thread -> (d, t-pair), coalesced u32 stores
            int d = tid >> 3, t0 = (tid & 7) * 2;
            u32 pa = (u32)f2bf(A2row[t0*32 + d]) | ((u32)f2bf(A2row[(t0+1)*32 + d]) << 16);
            u32 pb = (u32)f2bf(B2row[t0*32 + d]) | ((u32)f2bf(B2row[(t0+1)*32 + d]) << 16);
            *(u32*)(A2T + (size_t)d*8192 + n*16 + t0) = pa;
            *(u32*)(B2T + (size_t)d*8192 + n*16 + t0) = pb;
        }
    } else {
        int b = blockIdx.x - 512;            // 0..255
        int n0 = (b >> 4) * 32, m0 = (b & 15) * 32;
        __shared__ alignas(16) u16 s[32*520];  // [nl][ml*16+t], stride 520 (1040B=65*16)
        #pragma unroll
        for (int i = 0; i < 60; i++) {
            int e = tid + i*256;             // 0..15359 = 32 nl * 480
            int nl = e / 480; int rem = e - nl*480;
            int ml = rem / 15; int t = rem - ml*15;
            float v = adj[((size_t)(n0+nl)*512 + (m0+ml))*TT + t];
            s[nl*520 + ml*16 + t] = f2bf(v);
        }
        #pragma unroll
        for (int i = 0; i < 4; i++) {
            int e = tid + i*256; int nl = e >> 5, ml = e & 31;
            s[nl*520 + ml*16 + 15] = ((n0+nl) == (m0+ml)) ? (u16)0x3F80 : (u16)0;
        }
        __syncthreads();
        #pragma unroll
        for (int i = 0; i < 8; i++) {        // adjP: 32 rows x 1KB
            int c = tid + i*256;
            int nl = c >> 6, off = (c & 63) * 8;
            uint4 vv = *(const uint4*)(s + nl*520 + off);
            *(uint4*)(adjP + (size_t)(n0+nl)*8192 + m0*16 + off) = vv;
        }
        #pragma unroll
        for (int i = 0; i < 8; i++) {        // adjPT: 32 rows x 1KB (transposed)
            int c = tid + i*256;
            int ml = c >> 6, nlh = c & 63, nl = nlh >> 1, half = nlh & 1;
            uint4 vv = *(const uint4*)(s + nl*520 + ml*16 + half*8);
            *(uint4*)(adjPT + (size_t)(m0+ml)*8192 + (n0+nl)*16 + half*8) = vv;
        }
    }
}

// ---------------------------------------------------------------------------
// K2 (fused): per 16x16 logits tile, MFMA both directed dot-tensors and
// combine IN REGISTER (no G/H materialization):
//   accG[j]: D[n_rel][t] = sum_h Qb[n0+n_rel,h] * A1[m0+wv*4+j][t*32+h]
//   accH[j]: D[m_rel][t] = sum_h Qb[m0+m_rel,h] * B1[n0+wv*4+j][t*32+h]
//   l1[n,m] = sum_t adjP[n][m,t]*accG + adjPT[n][m,t]*QB[n,t]
//   l2[n,m] = sum_t adjP[n][m,t]*QAd[m,t] + adjPT[n][m,t]*accH
// t-sum via 16-lane xor-shuffles. L2 written transposed (L2T[m][n]).
// ---------------------------------------------------------------------------
__global__ __launch_bounds__(256) void k_logits(
    const u16* __restrict__ Qb, const u16* __restrict__ A1, const u16* __restrict__ B1,
    const u16* __restrict__ adjP, const u16* __restrict__ adjPT,
    const float* __restrict__ QAd, const float* __restrict__ QB,
    float* __restrict__ L1, float* __restrict__ L2T)
{
    const int m0 = blockIdx.x * 16, n0 = blockIdx.y * 16;
    const int tid = threadIdx.x;
    const int wv = tid >> 6, lane = tid & 63, l15 = lane & 15, quad = lane >> 4;
    __shared__ alignas(16) float sL1[16*17];
    __shared__ alignas(16) float sL2[16*17];

    bf8 afragN = *(const bf8*)(Qb + (size_t)(n0 + l15)*32 + quad*8);
    bf8 afragM = *(const bf8*)(Qb + (size_t)(m0 + l15)*32 + quad*8);

    f4 accG[4], accH[4];
    #pragma unroll
    for (int j = 0; j < 4; j++) {
        int m = m0 + wv*4 + j;
        int n = n0 + wv*4 + j;
        bf8 bG = *(const bf8*)(A1 + (size_t)m*512 + l15*32 + quad*8);
        bf8 bH = *(const bf8*)(B1 + (size_t)n*512 + l15*32 + quad*8);
        f4 z = {0.f,0.f,0.f,0.f};
        accG[j] = __builtin_amdgcn_mfma_f32_16x16x32_bf16(afragN, bG, z, 0, 0, 0);
        accH[j] = __builtin_amdgcn_mfma_f32_16x16x32_bf16(afragM, bH, z, 0, 0, 0);
    }

    // ---- combine G-side: l1[n = n0+quad*4+r][m = m0+wv*4+j] ----
    #pragma unroll
    for (int j = 0; j < 4; j++) {
        int m = m0 + wv*4 + j;
        #pragma unroll
        for (int r = 0; r < 4; r++) {
            int n = n0 + quad*4 + r;
            float a  = bf2f(adjP [(size_t)n*8192 + m*16 + l15]);
            float at = bf2f(adjPT[(size_t)n*8192 + m*16 + l15]);
            float v = a*accG[j][r] + at*QB[n*16 + l15];
            #pragma unroll
            for (int o = 1; o < 16; o <<= 1) v += __shfl_xor(v, o, 64);
            if (l15 == 0) sL1[(quad*4+r)*17 + wv*4 + j] = v;
        }
    }
    // ---- combine H-side: l2[n = n0+wv*4+j][m = m0+quad*4+r] -> sL2[m][n] ----
    #pragma unroll
    for (int j = 0; j < 4; j++) {
        int n = n0 + wv*4 + j;
        #pragma unroll
        for (int r = 0; r < 4; r++) {
            int m = m0 + quad*4 + r;
            float a  = bf2f(adjP [(size_t)n*8192 + m*16 + l15]);
            float at = bf2f(adjPT[(size_t)n*8192 + m*16 + l15]);
            float v = a*QAd[m*16 + l15] + at*accH[j][r];
            #pragma unroll
            for (int o = 1; o < 16; o <<= 1) v += __shfl_xor(v, o, 64);
            if (l15 == 0) sL2[(quad*4+r)*17 + wv*4 + j] = v;
        }
    }
    __syncthreads();
    int row = tid >> 4, col = tid & 15;
    L1 [(size_t)(n0+row)*NNODE + m0 + col] = sL1[row*17+col];
    L2T[(size_t)(m0+row)*NNODE + n0 + col] = sL2[row*17+col];
}

// ---------------------------------------------------------------------------
// K3: softmax over a 512-row + FUSED W-build and u/v reduction.
// blocks 0..511 (row j of L1 -> s1):  W1c[j][(k,t)] = s1[j,k]*adjP[j][(k,t)]
//                                     u1[j,t] = sum_k s1[j,k]*adjPT[j][(k,t)]
// blocks 512..1023 (row j of L2T -> s2T): same with W2c / v2.
// ---------------------------------------------------------------------------
__global__ __launch_bounds__(256) void k_softmax_w(
    const float* __restrict__ L1, const float* __restrict__ L2T,
    const u16* __restrict__ adjP, const u16* __restrict__ adjPT,
    u16* __restrict__ W1c, u16* __restrict__ W2c,
    float* __restrict__ u1, float* __restrict__ v2)
{
    int b = blockIdx.x, tid = threadIdx.x;
    bool first = b < NNODE;
    int j = first ? b : b - NNODE;
    const float* row = first ? (L1 + (size_t)j*NNODE) : (L2T + (size_t)j*NNODE);
    u16* W  = (first ? W1c : W2c) + (size_t)j*8192;
    float* uv = (first ? u1 : v2) + (size_t)j*TP;

    float v0 = row[tid], v1 = row[tid+256];
    float mx = fmaxf(v0, v1);
    #pragma unroll
    for (int o=32; o; o>>=1) mx = fmaxf(mx, __shfl_xor(mx, o, 64));
    __shared__ alignas(16) float red[4], red2[4], ur[4][16];
    int lane = tid & 63, wv = tid >> 6;
    if (!lane) red[wv] = mx;
    __syncthreads();
    mx = fmaxf(fmaxf(red[0],red[1]), fmaxf(red[2],red[3]));
    float e0 = __expf(v0 - mx), e1 = __expf(v1 - mx);
    float sm = e0 + e1;
    #pragma unroll
    for (int o=32; o; o>>=1) sm += __shfl_xor(sm, o, 64);
    if (!lane) red2[wv] = sm;
    __syncthreads();
    float inv = 1.0f / (red2[0]+red2[1]+red2[2]+red2[3]);
    float sa = e0*inv, sb = e1*inv;

    const u16* ap = adjP  + (size_t)j*8192;
    const u16* tp = adjPT + (size_t)j*8192;
    float u[16];
    #pragma unroll
    for (int t=0;t<16;t++) u[t]=0.f;
    #pragma unroll
    for (int half = 0; half < 2; half++) {
        int k = tid + half*256;
        float sv = half ? sb : sa;
        const uint4* p = (const uint4*)(ap + k*16);
        float av[16]; unpack8(p[0], av); unpack8(p[1], av+8);
        u16 o16[16];
        #pragma unroll
        for (int t=0;t<16;t++) o16[t] = f2bf(sv*av[t]);
        uint4* wp = (uint4*)(W + k*16);
        wp[0] = pack8(o16); wp[1] = pack8(o16+8);
        const uint4* q = (const uint4*)(tp + k*16);
        float tv[16]; unpack8(q[0], tv); unpack8(q[1], tv+8);
        #pragma unroll
        for (int t=0;t<16;t++) u[t] = fmaf(sv, tv[t], u[t]);
    }
    #pragma unroll
    for (int t=0;t<16;t++) {
        #pragma unroll
        for (int o=32; o; o>>=1) u[t] += __shfl_xor(u[t], o, 64);
    }
    if (!lane) {
        #pragma unroll
        for (int t=0;t<16;t++) ur[wv][t] = u[t];
    }
    __syncthreads();
    if (tid < 16) uv[tid] = ur[0][tid]+ur[1][tid]+ur[2][tid]+ur[3][tid];
}

// ---------------------------------------------------------------------------
// K4: MFMA GEMM temp[j,d] = W1c[j,:]·A2T[d,:] + W2c[j,:]·B2T[d,:]
// (M=512, N=32, K=8192 split into 16 k-chunks; partials to tempP)
// ---------------------------------------------------------------------------
__global__ __launch_bounds__(256) void k_gemm2(
    const u16* __restrict__ W1c, const u16* __restrict__ W2c,
    const u16* __restrict__ A2T, const u16* __restrict__ B2T,
    float* __restrict__ tempP)
{
    int tid = threadIdx.x;
    int wv = tid >> 6, lane = tid & 63, l15 = lane & 15, quad = lane >> 4;
    int w = blockIdx.x*4 + wv;             // 0..1023
    int kc = w & 15, dt = (w >> 4) & 1, jt = w >> 5;
    size_t aRow = (size_t)(jt*16 + l15)*8192;
    size_t bRow = (size_t)(dt*16 + l15)*8192;
    int kt0 = kc*512 + quad*8;
    f4 acc = {0.f, 0.f, 0.f, 0.f};
    #pragma unroll
    for (int s = 0; s < 16; s++) {
        int kt = kt0 + s*32;
        bf8 aw1 = *(const bf8*)(W1c + aRow + kt);
        bf8 ba2 = *(const bf8*)(A2T + bRow + kt);
        acc = __builtin_amdgcn_mfma_f32_16x16x32_bf16(aw1, ba2, acc, 0, 0, 0);
        bf8 aw2 = *(const bf8*)(W2c + aRow + kt);
        bf8 bb2 = *(const bf8*)(B2T + bRow + kt);
        acc = __builtin_amdgcn_mfma_f32_16x16x32_bf16(aw2, bb2, acc, 0, 0, 0);
    }
    #pragma unroll
    for (int r = 0; r < 4; r++)
        tempP[((size_t)kc*NNODE + jt*16 + quad*4 + r)*DD + dt*16 + l15] = acc[r];
}

// ---------------------------------------------------------------------------
// K5: reduce k-chunk partials, add self terms (u1·B2 + v2·A2), lrelu, f32 out.
// ---------------------------------------------------------------------------
__global__ __launch_bounds__(256) void k_final(
    const float* __restrict__ tempP, const float* __restrict__ u1, const float* __restrict__ v2,
    const u16* __restrict__ A2, const u16* __restrict__ B2, float* __restrict__ out)
{
    int j0 = blockIdx.x * 8;
    int tid = threadIdx.x;
    int j = tid >> 5, d = tid & 31;
    int jj = j0 + j;
    float acc = 0.f;
    #pragma unroll
    for (int kc=0;kc<16;kc++) acc += tempP[((size_t)kc*NNODE + jj)*DD + d];
    #pragma unroll
    for (int t=0;t<TP;t++) {
        acc += u1[(size_t)jj*TP + t] * bf2f(B2[(size_t)jj*512 + t*32 + d]);
        acc += v2[(size_t)jj*TP + t] * bf2f(A2[(size_t)jj*512 + t*32 + d]);
    }
    out[(size_t)jj*DD + d] = fmaxf(acc, 0.2f*acc);
}

// ---------------------------------------------------------------------------
extern "C" void kernel_launch(void* const* d_in, const int* in_sizes, int n_in,
                              void* d_out, int out_size, void* d_ws, size_t ws_size,
                              hipStream_t stream)
{
    (void)in_sizes; (void)n_in; (void)out_size; (void)ws_size;
    const float* x   = (const float*)d_in[0];
    const float* adj = (const float*)d_in[1];
    const float* W1  = (const float*)d_in[2];
    const float* W2  = (const float*)d_in[3];
    const float* W3  = (const float*)d_in[4];

    char* ws = (char*)d_ws;
    u16*   adjP = (u16*)(ws);                   // 8 MB
    u16*   adjPT= (u16*)(ws + 0x800000);        // 8 MB
    u16*   W1c  = (u16*)(ws + 0x1000000);       // 8 MB
    u16*   W2c  = (u16*)(ws + 0x1800000);       // 8 MB
    u16*   A1   = (u16*)(ws + 0x2000000);       // 512 KB each
    u16*   B1   = (u16*)(ws + 0x2080000);
    u16*   A2   = (u16*)(ws + 0x2100000);
    u16*   B2   = (u16*)(ws + 0x2180000);
    u16*   A2T  = (u16*)(ws + 0x2200000);
    u16*   B2T  = (u16*)(ws + 0x2280000);
    u16*   Qb   = (u16*)(ws + 0x2300000);       // 32 KB
    float* QAd  = (float*)(ws + 0x2310000);
    float* QB   = (float*)(ws + 0x2320000);
    float* u1   = (float*)(ws + 0x2330000);
    float* v2   = (float*)(ws + 0x2340000);
    float* L1   = (float*)(ws + 0x2400000);     // 1 MB
    float* L2T  = (float*)(ws + 0x2500000);     // 1 MB
    float* tempP= (float*)(ws + 0x2600000);     // 1 MB

    k_prep_adjp<<<768, 256, 0, stream>>>(x, W1, W2, W3, adj,
                                         A1, B1, A2, B2, A2T, B2T, Qb, QAd, QB, adjP, adjPT);
    k_logits<<<dim3(32,32), 256, 0, stream>>>(Qb, A1, B1, adjP, adjPT, QAd, QB, L1, L2T);
    k_softmax_w<<<1024, 256, 0, stream>>>(L1, L2T, adjP, adjPT, W1c, W2c, u1, v2);
    k_gemm2<<<256, 256, 0, stream>>>(W1c, W2c, A2T, B2T, tempP);
    k_final<<<64, 256, 0, stream>>>(tempP, u1, v2, A2, B2, (float*)d_out);
}